// Round 2
// baseline (249.037 us; speedup 1.0000x reference)
//
#include <hip/hip_runtime.h>

#define C_IN   1024
#define C4     (C_IN / 4)   // 256 float4 per row
#define KCNT   256
#define ROWS   16
#define TAU    0.02f        // fp32 gap below which we re-check in fp64

// ---------------------------------------------------------------------------
// Prep: transpose keys into [c4][k] float4 layout (coalesced per-c4 access by
// key-owning threads) and compute k2[k] = ||key_k||^2 (fp32, fast path only).
// ---------------------------------------------------------------------------
__global__ __launch_bounds__(256) void prep_kernel(const float* __restrict__ keys,
                                                   float4* __restrict__ keysT4,
                                                   float* __restrict__ k2) {
    const int k = blockIdx.x;
    const int t = threadIdx.x;
    float4 v = ((const float4*)keys)[(size_t)k * C4 + t];
    keysT4[(size_t)t * KCNT + k] = v;
    float s = v.x * v.x + v.y * v.y + v.z * v.z + v.w * v.w;
#pragma unroll
    for (int off = 32; off; off >>= 1) s += __shfl_xor(s, off, 64);
    __shared__ float ws[4];
    if ((t & 63) == 0) ws[t >> 6] = s;
    __syncthreads();
    if (t == 0) k2[k] = ws[0] + ws[1] + ws[2] + ws[3];
}

// ---------------------------------------------------------------------------
// Main: block = 16 rows of x staged in 64 KB LDS. Thread t owns key k=t.
// score = k2[k] - 2*dot(x_r, key_k)   (x^2 omitted: argmin-invariant).
// Top-2 per row; rows with (2nd - best) < TAU re-scored exactly in fp64.
// Output = gather of values rows -> bit-exact vs reference when argmin exact.
// ---------------------------------------------------------------------------
template <bool WST>
__global__ __launch_bounds__(256) void codebook_kernel(
    const float* __restrict__ x,
    const float* __restrict__ keys,
    const float4* __restrict__ keysT4,
    const float* __restrict__ k2,
    const float* __restrict__ values,
    float* __restrict__ out) {
    __shared__ float xs[ROWS * C_IN];  // 64 KB; partially reused for scratch
    float4* xs4 = (float4*)xs;

    const int t = threadIdx.x;
    const int row0 = blockIdx.x * ROWS;

    // Stage 16 rows of x (contiguous): 4096 float4, 16 per thread, coalesced.
    const float4* x4 = (const float4*)x;
#pragma unroll
    for (int i = 0; i < ROWS; ++i)
        xs4[i * C4 + t] = x4[(size_t)row0 * C4 + i * C4 + t];
    __syncthreads();

    const int k = t;
    float acc[ROWS];
#pragma unroll
    for (int r = 0; r < ROWS; ++r) acc[r] = 0.f;
    float k2acc = 0.f;

    const float4* kptr = WST ? (keysT4 + k) : (((const float4*)keys) + (size_t)k * C4);

    for (int c4 = 0; c4 < C4; ++c4) {
        float4 kv = WST ? kptr[(size_t)c4 * KCNT] : kptr[c4];
        if (!WST) k2acc += kv.x * kv.x + kv.y * kv.y + kv.z * kv.z + kv.w * kv.w;
#pragma unroll
        for (int r = 0; r < ROWS; ++r) {
            float4 xv = xs4[r * C4 + c4];  // broadcast (same addr across lanes)
            acc[r] = fmaf(kv.x, xv.x, acc[r]);
            acc[r] = fmaf(kv.y, xv.y, acc[r]);
            acc[r] = fmaf(kv.z, xv.z, acc[r]);
            acc[r] = fmaf(kv.w, xv.w, acc[r]);
        }
    }
    const float k2v = WST ? k2[k] : k2acc;

    __syncthreads();  // all reads of xs done; reuse front of xs as scratch
    float* ssc  = xs;                    // scores [ROWS][KCNT] = 16 KB
    int*   sidx = (int*)(xs + ROWS * KCNT);        // 16 ints
    float* sgap = xs + ROWS * KCNT + ROWS;          // 16 floats
    double* dva = (double*)(xs + ROWS * KCNT + 2 * ROWS);  // 4 doubles (8B-aligned)
    int*    dia = (int*)(xs + ROWS * KCNT + 2 * ROWS + 8); // 4 ints

#pragma unroll
    for (int r = 0; r < ROWS; ++r) ssc[r * KCNT + k] = k2v - 2.f * acc[r];
    __syncthreads();

    // Top-2 argmin per row. Wave w handles rows [4w, 4w+4). First-occurrence
    // tie-break (ascending index scan + smaller-idx wins on equal value).
    const int wave = t >> 6, lane = t & 63;
#pragma unroll
    for (int i = 0; i < ROWS / 4; ++i) {
        const int r = wave * (ROWS / 4) + i;
        float v1 = ssc[r * KCNT + lane];
        int   i1 = lane;
        float v2 = 1e30f;
#pragma unroll
        for (int j = 1; j < 4; ++j) {
            float c = ssc[r * KCNT + lane + 64 * j];
            if (c < v1) { v2 = v1; v1 = c; i1 = lane + 64 * j; }
            else        { v2 = fminf(v2, c); }
        }
#pragma unroll
        for (int off = 32; off; off >>= 1) {
            float w1 = __shfl_xor(v1, off, 64);
            int   j1 = __shfl_xor(i1, off, 64);
            float w2 = __shfl_xor(v2, off, 64);
            if (w1 < v1 || (w1 == v1 && j1 < i1)) { v2 = fminf(v1, w2); v1 = w1; i1 = j1; }
            else                                  { v2 = fminf(v2, w1); }
        }
        if (lane == 0) { sidx[r] = i1; sgap[r] = v2 - v1; }
    }
    __syncthreads();

    // Exact fp64 refinement for near-tie rows (block-uniform branch: sgap is
    // a broadcast LDS read). Expected ~19 flagged rows across the whole grid.
    for (int fr = 0; fr < ROWS; ++fr) {
        if (sgap[fr] < TAU) {
            double dotd = 0.0, k2d = 0.0;
            const float4* xrow = x4 + (size_t)(row0 + fr) * C4;
#pragma unroll 4
            for (int c4 = 0; c4 < C4; ++c4) {
                float4 xv = xrow[c4];
                float4 kv = WST ? keysT4[(size_t)c4 * KCNT + t]
                                : ((const float4*)keys)[(size_t)t * C4 + c4];
                dotd += (double)kv.x * (double)xv.x; k2d += (double)kv.x * (double)kv.x;
                dotd += (double)kv.y * (double)xv.y; k2d += (double)kv.y * (double)kv.y;
                dotd += (double)kv.z * (double)xv.z; k2d += (double)kv.z * (double)kv.z;
                dotd += (double)kv.w * (double)xv.w; k2d += (double)kv.w * (double)kv.w;
            }
            double sd = k2d - 2.0 * dotd;
            int    si = t;
#pragma unroll
            for (int off = 32; off; off >>= 1) {
                double od = __shfl_xor(sd, off, 64);
                int    oi = __shfl_xor(si, off, 64);
                if (od < sd || (od == sd && oi < si)) { sd = od; si = oi; }
            }
            if ((t & 63) == 0) { dva[wave] = sd; dia[wave] = si; }
            __syncthreads();
            if (t == 0) {
                double b = dva[0]; int bi = dia[0];
#pragma unroll
                for (int w = 1; w < 4; ++w)
                    if (dva[w] < b || (dva[w] == b && dia[w] < bi)) { b = dva[w]; bi = dia[w]; }
                sidx[fr] = bi;
            }
            __syncthreads();
        }
    }

    // Gather: out[row0+r] = values[sidx[r]] (256 float4 per row, coalesced).
    const float4* v4p = (const float4*)values;
    float4* o4 = (float4*)out;
#pragma unroll
    for (int r = 0; r < ROWS; ++r) {
        const int idx = sidx[r];
        o4[(size_t)(row0 + r) * C4 + t] = v4p[(size_t)idx * C4 + t];
    }
}

extern "C" void kernel_launch(void* const* d_in, const int* in_sizes, int n_in,
                              void* d_out, int out_size, void* d_ws, size_t ws_size,
                              hipStream_t stream) {
    const float* x      = (const float*)d_in[0];
    const float* keys   = (const float*)d_in[1];
    const float* values = (const float*)d_in[2];
    float* out = (float*)d_out;

    const int nrows = in_sizes[0] / C_IN;  // 16384
    const size_t need = (size_t)KCNT * C_IN * sizeof(float) + KCNT * sizeof(float);

    if (d_ws != nullptr && ws_size >= need) {
        float4* keysT4 = (float4*)d_ws;
        float* k2 = (float*)((char*)d_ws + (size_t)KCNT * C_IN * sizeof(float));
        prep_kernel<<<KCNT, 256, 0, stream>>>(keys, keysT4, k2);
        codebook_kernel<true><<<nrows / ROWS, 256, 0, stream>>>(
            x, keys, keysT4, k2, values, out);
    } else {
        codebook_kernel<false><<<nrows / ROWS, 256, 0, stream>>>(
            x, keys, nullptr, nullptr, values, out);
    }
}

// Round 3
// 131.457 us; speedup vs baseline: 1.8944x; 1.8944x over previous
//
#include <hip/hip_runtime.h>

#define C_IN   1024
#define C4     (C_IN / 4)      // 256 float4 per row (also C_out/4)
#define KCNT   256
#define TAU    0.05f           // split-bf16 score error ~1e-3 -> 50x margin

#define MB     64              // rows per block (4 waves x 16 rows)
#define KC     64              // k-chunk staged in LDS
#define NCHUNK (C_IN / KC)     // 16

typedef __attribute__((ext_vector_type(8))) short bf16x8;
typedef __attribute__((ext_vector_type(4))) float f32x4;

static __device__ __forceinline__ unsigned short f2bf(float f) {
    union { float f; unsigned u; } v; v.f = f;
    unsigned r = v.u + 0x7fffu + ((v.u >> 16) & 1u);   // RNE
    return (unsigned short)(r >> 16);
}
static __device__ __forceinline__ float bf2f(unsigned short h) {
    union { unsigned u; float f; } v; v.u = (unsigned)h << 16;
    return v.f;
}
static __device__ __forceinline__ void load_lds16(const void* g, void* l) {
    __builtin_amdgcn_global_load_lds(
        (const __attribute__((address_space(1))) unsigned int*)g,
        (__attribute__((address_space(3))) unsigned int*)l, 16, 0, 0);
}

// ---------------------------------------------------------------------------
// Prep: keys -> hi/lo bf16, written as the pre-swizzled linear LDS image:
// per chunk region (32 KB): byte = key*128 + ((kk*2) ^ ((key&7)<<4)).
// (key&7 pattern makes the main kernel's ds_read_b128 ~2-way conflict = free.)
// Also k2[key] = ||key||^2 in fp32.
// ---------------------------------------------------------------------------
__global__ __launch_bounds__(256) void prep_mfma(const float* __restrict__ keys,
        unsigned short* __restrict__ kws_hi, unsigned short* __restrict__ kws_lo,
        float* __restrict__ k2) {
    const int key = blockIdx.x, t = threadIdx.x;
    float4 v = ((const float4*)keys)[(size_t)key * C4 + t];
    float f[4] = {v.x, v.y, v.z, v.w};
    short h[4], lo[4];
#pragma unroll
    for (int i = 0; i < 4; ++i) {
        unsigned short hh = f2bf(f[i]);
        h[i] = (short)hh;
        lo[i] = (short)f2bf(f[i] - bf2f(hh));   // exact residual (Sterbenz)
    }
    const int c = t * 4, chunk = c >> 6, kk = c & 63;
    const size_t boff = (size_t)chunk * 32768 + (size_t)key * 128
                      + (size_t)((kk * 2) ^ ((key & 7) << 4));
    *(short4*)((char*)kws_hi + boff) = make_short4(h[0], h[1], h[2], h[3]);
    *(short4*)((char*)kws_lo + boff) = make_short4(lo[0], lo[1], lo[2], lo[3]);

    float s = f[0]*f[0] + f[1]*f[1] + f[2]*f[2] + f[3]*f[3];
#pragma unroll
    for (int off = 32; off; off >>= 1) s += __shfl_xor(s, off, 64);
    __shared__ float ws[4];
    if ((t & 63) == 0) ws[t >> 6] = s;
    __syncthreads();
    if (t == 0) k2[key] = ws[0] + ws[1] + ws[2] + ws[3];
}

// ---------------------------------------------------------------------------
// Main: block = 64 rows x 256 keys. Wave w owns rows [w*16, w*16+16).
// K-loop: stage B chunk (keys hi+lo, 64 KB) in LDS; A frags global->reg with
// on-the-fly hi/lo split; 3-product MFMA accumulate (hi*hi + hi*lo + lo*hi).
// Epilogue: score = k2 - 2*dot, per-row top-2, fp64 refine for gap < TAU,
// gather values rows.
// ---------------------------------------------------------------------------
__global__ __launch_bounds__(256) void vq_mfma(
        const float* __restrict__ x, const float* __restrict__ keys,
        const unsigned short* __restrict__ kws_hi,
        const unsigned short* __restrict__ kws_lo,
        const float* __restrict__ k2g, const float* __restrict__ values,
        float* __restrict__ out) {
    __shared__ char smem[65536];     // [Bhi 32KB][Blo 32KB]; reused in epilogue
    char* Bhi = smem;
    char* Blo = smem + 32768;

    const int t = threadIdx.x;
    const int w = t >> 6, l = t & 63;
    const int lrow = l & 15, lgrp = l >> 4;
    const int row0 = blockIdx.x * MB;

    f32x4 acc[16];
#pragma unroll
    for (int i = 0; i < 16; ++i) acc[i] = (f32x4){0.f, 0.f, 0.f, 0.f};

    // A source: this lane's row (MFMA A layout: row = lane&15, k = (lane>>4)*8+i)
    const float* xrow = x + (size_t)(row0 + w * 16 + lrow) * C_IN;
    const int bOff = lrow * 128;          // B row base (tile 0)
    const int xorv = (l & 7) << 4;        // (key&7)<<4 == (lrow&7)<<4

    for (int ch = 0; ch < NCHUNK; ++ch) {
        // ---- stage B chunk: wave w copies its 8 KB slice of hi and lo
        const char* sH = (const char*)kws_hi + (size_t)ch * 32768 + w * 8192 + l * 16;
        const char* sL = (const char*)kws_lo + (size_t)ch * 32768 + w * 8192 + l * 16;
        char* dH = Bhi + w * 8192;
        char* dL = Blo + w * 8192;
#pragma unroll
        for (int j = 0; j < 8; ++j) {
            load_lds16(sH + j * 1024, dH + j * 1024);
            load_lds16(sL + j * 1024, dL + j * 1024);
        }
        // ---- A fragments: 8 contiguous c-elems per lane per ks, hi/lo split
        bf16x8 ah[2], al[2];
#pragma unroll
        for (int ks = 0; ks < 2; ++ks) {
            const float* xp = xrow + ch * KC + ks * 32 + lgrp * 8;
            float4 xa = *(const float4*)xp;
            float4 xb = *(const float4*)(xp + 4);
            float f[8] = {xa.x, xa.y, xa.z, xa.w, xb.x, xb.y, xb.z, xb.w};
#pragma unroll
            for (int i = 0; i < 8; ++i) {
                unsigned short hh = f2bf(f[i]);
                ah[ks][i] = (short)hh;
                al[ks][i] = (short)f2bf(f[i] - bf2f(hh));
            }
        }
        __syncthreads();   // barrier drains vmcnt -> B resident

#pragma unroll
        for (int ks = 0; ks < 2; ++ks) {
            const int kb = bOff + ((ks * 64 + lgrp * 16) ^ xorv);
#pragma unroll
            for (int kt = 0; kt < 16; ++kt) {
                bf16x8 bh = *(const bf16x8*)(Bhi + kt * 2048 + kb);
                bf16x8 bl = *(const bf16x8*)(Blo + kt * 2048 + kb);
                acc[kt] = __builtin_amdgcn_mfma_f32_16x16x32_bf16(ah[ks], bh, acc[kt], 0, 0, 0);
                acc[kt] = __builtin_amdgcn_mfma_f32_16x16x32_bf16(ah[ks], bl, acc[kt], 0, 0, 0);
                acc[kt] = __builtin_amdgcn_mfma_f32_16x16x32_bf16(al[ks], bh, acc[kt], 0, 0, 0);
            }
        }
        __syncthreads();   // all reads done before next chunk overwrites B
    }

    // ---- epilogue scratch overlays B region (B dead now)
    float*  sgap = (float*)smem;           // 64 floats
    int*    sidx = (int*)(smem + 256);     // 64 ints
    double* dva  = (double*)(smem + 512);  // 4 doubles (8B aligned)
    int*    dia  = (int*)(smem + 544);     // 4 ints

    // top-2 per row: lane holds rows lgrp*4+j (C layout: col=lane&15,
    // row=(lane>>4)*4+reg), key = kt*16 + lrow.
#pragma unroll
    for (int j = 0; j < 4; ++j) {
        float v1 = 1e30f, v2 = 1e30f; int i1 = 0;
#pragma unroll
        for (int kt = 0; kt < 16; ++kt) {
            float s = k2g[kt * 16 + lrow] - 2.f * acc[kt][j];
            if (s < v1) { v2 = v1; v1 = s; i1 = kt * 16 + lrow; }
            else        { v2 = fminf(v2, s); }
        }
#pragma unroll
        for (int off = 1; off < 16; off <<= 1) {   // reduce the 16-lane group
            float w1 = __shfl_xor(v1, off, 64);
            int   j1 = __shfl_xor(i1, off, 64);
            float w2 = __shfl_xor(v2, off, 64);
            if (w1 < v1 || (w1 == v1 && j1 < i1)) { v2 = fminf(v1, w2); v1 = w1; i1 = j1; }
            else                                  { v2 = fminf(v2, w1); }
        }
        if (lrow == 0) {
            sidx[w * 16 + lgrp * 4 + j] = i1;
            sgap[w * 16 + lgrp * 4 + j] = v2 - v1;
        }
    }
    __syncthreads();

    // fp64 refinement for near-tie rows (block-uniform branch; rare)
    const float4* x4 = (const float4*)x;
    for (int fr = 0; fr < MB; ++fr) {
        if (sgap[fr] < TAU) {
            double dotd = 0.0, k2d = 0.0;
            const float4* xr = x4 + (size_t)(row0 + fr) * C4;
            const float4* kr = (const float4*)keys + (size_t)t * C4;
#pragma unroll 4
            for (int c4 = 0; c4 < C4; ++c4) {
                float4 xv = xr[c4];
                float4 kv = kr[c4];
                dotd += (double)kv.x * (double)xv.x; k2d += (double)kv.x * (double)kv.x;
                dotd += (double)kv.y * (double)xv.y; k2d += (double)kv.y * (double)kv.y;
                dotd += (double)kv.z * (double)xv.z; k2d += (double)kv.z * (double)kv.z;
                dotd += (double)kv.w * (double)xv.w; k2d += (double)kv.w * (double)kv.w;
            }
            double sd = k2d - 2.0 * dotd;
            int    si = t;
#pragma unroll
            for (int off = 32; off; off >>= 1) {
                double od = __shfl_xor(sd, off, 64);
                int    oi = __shfl_xor(si, off, 64);
                if (od < sd || (od == sd && oi < si)) { sd = od; si = oi; }
            }
            if (l == 0) { dva[w] = sd; dia[w] = si; }
            __syncthreads();
            if (t == 0) {
                double b = dva[0]; int bi = dia[0];
#pragma unroll
                for (int ww = 1; ww < 4; ++ww)
                    if (dva[ww] < b || (dva[ww] == b && dia[ww] < bi)) { b = dva[ww]; bi = dia[ww]; }
                sidx[fr] = bi;
            }
            __syncthreads();
        }
    }

    // gather values rows -> out (coalesced, 4 KB per row)
    const float4* v4 = (const float4*)values;
    float4* o4 = (float4*)out;
    for (int r = 0; r < MB; ++r) {
        const int idx = sidx[r];
        o4[(size_t)(row0 + r) * C4 + t] = v4[(size_t)idx * C4 + t];
    }
}

// ---------------------------------------------------------------------------
// Fallback (no/small workspace): round-2 validated fp32 path.
// ---------------------------------------------------------------------------
#define FB_ROWS 16
__global__ __launch_bounds__(256) void codebook_fallback(
    const float* __restrict__ x, const float* __restrict__ keys,
    const float* __restrict__ values, float* __restrict__ out) {
    __shared__ float xs[FB_ROWS * C_IN];
    float4* xs4 = (float4*)xs;
    const int t = threadIdx.x;
    const int row0 = blockIdx.x * FB_ROWS;
    const float4* x4 = (const float4*)x;
#pragma unroll
    for (int i = 0; i < FB_ROWS; ++i)
        xs4[i * C4 + t] = x4[(size_t)row0 * C4 + i * C4 + t];
    __syncthreads();

    float acc[FB_ROWS];
#pragma unroll
    for (int r = 0; r < FB_ROWS; ++r) acc[r] = 0.f;
    float k2acc = 0.f;
    const float4* kptr = ((const float4*)keys) + (size_t)t * C4;
    for (int c4 = 0; c4 < C4; ++c4) {
        float4 kv = kptr[c4];
        k2acc += kv.x * kv.x + kv.y * kv.y + kv.z * kv.z + kv.w * kv.w;
#pragma unroll
        for (int r = 0; r < FB_ROWS; ++r) {
            float4 xv = xs4[r * C4 + c4];
            acc[r] = fmaf(kv.x, xv.x, acc[r]);
            acc[r] = fmaf(kv.y, xv.y, acc[r]);
            acc[r] = fmaf(kv.z, xv.z, acc[r]);
            acc[r] = fmaf(kv.w, xv.w, acc[r]);
        }
    }
    __syncthreads();
    float* ssc  = xs;
    int*   sidx = (int*)(xs + FB_ROWS * KCNT);
    float* sgap = xs + FB_ROWS * KCNT + FB_ROWS;
    double* dva = (double*)(xs + FB_ROWS * KCNT + 2 * FB_ROWS);
    int*    dia = (int*)(xs + FB_ROWS * KCNT + 2 * FB_ROWS + 8);
#pragma unroll
    for (int r = 0; r < FB_ROWS; ++r) ssc[r * KCNT + t] = k2acc - 2.f * acc[r];
    __syncthreads();
    const int wave = t >> 6, lane = t & 63;
#pragma unroll
    for (int i = 0; i < FB_ROWS / 4; ++i) {
        const int r = wave * (FB_ROWS / 4) + i;
        float v1 = ssc[r * KCNT + lane];
        int   i1 = lane;
        float v2 = 1e30f;
#pragma unroll
        for (int j = 1; j < 4; ++j) {
            float c = ssc[r * KCNT + lane + 64 * j];
            if (c < v1) { v2 = v1; v1 = c; i1 = lane + 64 * j; }
            else        { v2 = fminf(v2, c); }
        }
#pragma unroll
        for (int off = 32; off; off >>= 1) {
            float w1 = __shfl_xor(v1, off, 64);
            int   j1 = __shfl_xor(i1, off, 64);
            float w2 = __shfl_xor(v2, off, 64);
            if (w1 < v1 || (w1 == v1 && j1 < i1)) { v2 = fminf(v1, w2); v1 = w1; i1 = j1; }
            else                                  { v2 = fminf(v2, w1); }
        }
        if (lane == 0) { sidx[r] = i1; sgap[r] = v2 - v1; }
    }
    __syncthreads();
    for (int fr = 0; fr < FB_ROWS; ++fr) {
        if (sgap[fr] < 0.02f) {
            double dotd = 0.0, k2d = 0.0;
            const float4* xrow = x4 + (size_t)(row0 + fr) * C4;
#pragma unroll 4
            for (int c4 = 0; c4 < C4; ++c4) {
                float4 xv = xrow[c4];
                float4 kv = ((const float4*)keys)[(size_t)t * C4 + c4];
                dotd += (double)kv.x * (double)xv.x; k2d += (double)kv.x * (double)kv.x;
                dotd += (double)kv.y * (double)xv.y; k2d += (double)kv.y * (double)kv.y;
                dotd += (double)kv.z * (double)xv.z; k2d += (double)kv.z * (double)kv.z;
                dotd += (double)kv.w * (double)xv.w; k2d += (double)kv.w * (double)kv.w;
            }
            double sd = k2d - 2.0 * dotd;
            int    si = t;
#pragma unroll
            for (int off = 32; off; off >>= 1) {
                double od = __shfl_xor(sd, off, 64);
                int    oi = __shfl_xor(si, off, 64);
                if (od < sd || (od == sd && oi < si)) { sd = od; si = oi; }
            }
            if ((t & 63) == 0) { dva[wave] = sd; dia[wave] = si; }
            __syncthreads();
            if (t == 0) {
                double b = dva[0]; int bi = dia[0];
#pragma unroll
                for (int ww = 1; ww < 4; ++ww)
                    if (dva[ww] < b || (dva[ww] == b && dia[ww] < bi)) { b = dva[ww]; bi = dia[ww]; }
                sidx[fr] = bi;
            }
            __syncthreads();
        }
    }
    const float4* v4p = (const float4*)values;
    float4* o4 = (float4*)out;
#pragma unroll
    for (int r = 0; r < FB_ROWS; ++r) {
        const int idx = sidx[r];
        o4[(size_t)(row0 + r) * C4 + t] = v4p[(size_t)idx * C4 + t];
    }
}

extern "C" void kernel_launch(void* const* d_in, const int* in_sizes, int n_in,
                              void* d_out, int out_size, void* d_ws, size_t ws_size,
                              hipStream_t stream) {
    const float* x      = (const float*)d_in[0];
    const float* keys   = (const float*)d_in[1];
    const float* values = (const float*)d_in[2];
    float* out = (float*)d_out;

    const int nrows = in_sizes[0] / C_IN;  // 16384
    const size_t need = 2u * 524288u + 1024u;  // kws_hi + kws_lo + k2

    if (d_ws != nullptr && ws_size >= need && (nrows % MB) == 0) {
        unsigned short* kh = (unsigned short*)d_ws;
        unsigned short* kl = (unsigned short*)((char*)d_ws + 524288);
        float* k2 = (float*)((char*)d_ws + 1048576);
        prep_mfma<<<KCNT, 256, 0, stream>>>(keys, kh, kl, k2);
        vq_mfma<<<nrows / MB, 256, 0, stream>>>(x, keys, kh, kl, k2, values, out);
    } else {
        codebook_fallback<<<nrows / FB_ROWS, 256, 0, stream>>>(x, keys, values, out);
    }
}